// Round 1
// baseline (168.838 us; speedup 1.0000x reference)
//
#include <hip/hip_runtime.h>
#include <hip/hip_bf16.h>
#include <hip/hip_fp16.h>

#define BATCH_N 256
#define IN_F    16384
#define OUT_F   16384
#define CAP     128              // edge slots per row (mean 61, 8.6 sigma margin)
#define EPB     2048             // edges per partition block (489 blocks)
#define TBLK    1024             // transpose blocks inside fused prep kernel

typedef unsigned int u32x4 __attribute__((ext_vector_type(4)));
typedef float f32x4 __attribute__((ext_vector_type(4)));

// ---------------- fused prep: direct edge scatter (blocks 0..npart-1) +
//                  transpose_x (blocks npart..npart+TBLK-1) ----------------
// Edge record (4 B): (col << 16) | fp16(val). Row implied by bin.
// Scatter goes straight to the per-row [OUT][CAP] bins via one global
// atomicAdd per edge (61 edges/counter avg -> negligible contention); edges
// array is pre-zeroed so slots >= count decode to val=0 and contribute 0.

__global__ void prep_kernel(const float* __restrict__ x,
                            __hip_bfloat16* __restrict__ xTh,
                            const int* __restrict__ rows,
                            const int* __restrict__ cols,
                            const float* __restrict__ vals, int nnz, int npart,
                            unsigned int* __restrict__ edges,   // [OUT][CAP]
                            int* __restrict__ counts) {         // [OUT]
    __shared__ float tile[64 * 65];
    int t = threadIdx.x;
    if ((int)blockIdx.x < npart) {
        // ---- direct scatter of EPB edges into per-row bins ----
        int i0 = blockIdx.x * EPB;
#pragma unroll
        for (int k = 0; k < 8; ++k) {
            int i = i0 + k * 256 + t;
            if (i < nnz) {
                int r = rows[i];
                unsigned int rec = ((unsigned int)cols[i] << 16) |
                    (unsigned int)__half_as_ushort(__float2half(vals[i]));
                int p = atomicAdd(&counts[r], 1);
                if (p < CAP)
                    edges[(size_t)r * CAP + p] = rec;
            }
        }
    } else {
        // ---- transpose + bf16 quantize: x [256][IN] -> xTh [2][IN][128] ----
        int bid = blockIdx.x - npart;
        int i0 = (bid & 255) * 64;
        int b0 = (bid >> 8) * 64;
        int tx4 = t & 15;                  // float4 index within 64-col tile
        int r16 = t >> 4;                  // 0..15
#pragma unroll
        for (int k = 0; k < 4; ++k) {
            int row = r16 + k * 16;        // batch row within tile
            f32x4 v = *(const f32x4*)(x + (size_t)(b0 + row) * IN_F + i0 + tx4 * 4);
            tile[row * 65 + tx4 * 4 + 0] = v.x;
            tile[row * 65 + tx4 * 4 + 1] = v.y;
            tile[row * 65 + tx4 * 4 + 2] = v.z;
            tile[row * 65 + tx4 * 4 + 3] = v.w;
        }
        __syncthreads();
        int tx = t & 63, ty = t >> 6;
        int h = b0 >> 7, j0 = b0 & 127;
#pragma unroll
        for (int k = 0; k < 64; k += 4) {
            int col = i0 + ty + k;
            xTh[((size_t)h * IN_F + col) * 128 + j0 + tx] =
                __float2bfloat16(tile[tx * 65 + ty + k]);
        }
    }
}

// ---------------- accumulate + direct transposed output ----------------
// 2048 blocks: rowgroup = blk>>1 (16 rows), h = blk&1 (round-robin XCD dispatch
// keeps one 4 MB xh half per XCD L2). Scalar edge lists with software-pipelined
// s_load prefetch; LDS slab; final out written directly (64 B line per store).
// counts[] holds raw counts now: clamp to CAP, round up to 8 (pad slots are
// zero records -> contribute 0).

__global__ void accum_kernel(const unsigned int* __restrict__ xh0, // [2][IN][64] bf162
                             const unsigned int* __restrict__ edges, // [OUT][CAP]
                             const int*   __restrict__ counts,    // raw counts
                             const float* __restrict__ bias,
                             float* __restrict__ out) {            // [256][OUT]
    __shared__ float slab[128][17];     // [batch_in_half][row_local], pad 17
    int blk = blockIdx.x;
    int h = blk & 1;
    int o0 = (blk >> 1) * 16;
    int w = threadIdx.x >> 6;           // wave 0..3
    int lane = threadIdx.x & 63;
    const unsigned int* xh = xh0 + (size_t)h * IN_F * 64;
#pragma unroll
    for (int rr = 0; rr < 4; ++rr) {
        int rl = w * 4 + rr;
        int o = __builtin_amdgcn_readfirstlane(o0 + rl);
        int cnt = counts[o];            // uniform (raw)
        if (cnt > CAP) cnt = CAP;
        int n = (cnt + 7) & ~7;
        const u32x4* el4 = (const u32x4*)(edges + (size_t)o * CAP);
        float ax = 0.f, ay = 0.f;
        u32x4 ca = el4[0], cb = el4[1];
        for (int j = 0; j < n; j += 8) {
            u32x4 na = el4[(j >> 2) + 2];      // prefetch next chunk (may overread
            u32x4 nb = el4[(j >> 2) + 3];      //  <=32 B past row; region mapped)
            unsigned int e[8];
            e[0] = ca.x; e[1] = ca.y; e[2] = ca.z; e[3] = ca.w;
            e[4] = cb.x; e[5] = cb.y; e[6] = cb.z; e[7] = cb.w;
            unsigned int g[8];
#pragma unroll
            for (int k = 0; k < 8; ++k) {
                const unsigned int* p = xh + ((e[k] >> 16) << 6);  // scalar base
                g[k] = p[lane];                                     // vgpr offset
            }
#pragma unroll
            for (int k = 0; k < 8; ++k) {
                float v = __half2float(__ushort_as_half((unsigned short)(e[k] & 0xffffu)));
                ax += __uint_as_float(g[k] << 16) * v;
                ay += __uint_as_float(g[k] & 0xffff0000u) * v;
            }
            ca = na; cb = nb;
        }
        float bv = bias[o];
        slab[2 * lane + 0][rl] = ax + bv;   // batch 2t   of this half
        slab[2 * lane + 1][rl] = ay + bv;   // batch 2t+1
    }
    __syncthreads();
    // write phase: 512 float4 items (128 batches x 4 quarters), 2 per thread
#pragma unroll
    for (int it = 0; it < 2; ++it) {
        int item = threadIdx.x + it * 256;
        int bl = item >> 2;             // batch within half, 0..127
        int q = item & 3;               // quarter of 16 rows
        f32x4 v;
        v.x = slab[bl][q * 4 + 0];
        v.y = slab[bl][q * 4 + 1];
        v.z = slab[bl][q * 4 + 2];
        v.w = slab[bl][q * 4 + 3];
        __builtin_nontemporal_store(v,
            (f32x4*)(out + (size_t)(h * 128 + bl) * OUT_F + o0 + q * 4));
    }
}

extern "C" void kernel_launch(void* const* d_in, const int* in_sizes, int n_in,
                              void* d_out, int out_size, void* d_ws, size_t ws_size,
                              hipStream_t stream) {
    const float* x     = (const float*)d_in[0];
    const float* wvals = (const float*)d_in[1];
    const float* bias  = (const float*)d_in[2];
    const int*   rows  = (const int*)d_in[3];
    const int*   cols  = (const int*)d_in[4];
    float* out = (float*)d_out;
    int nnz = in_sizes[1];

    const size_t MB = 1024 * 1024;
    char* ws = (char*)d_ws;
    __hip_bfloat16* xTh = (__hip_bfloat16*)(ws);        // [0, 8 MB): [2][IN][128] bf16
    unsigned int* edges = (unsigned int*)(ws + 8 * MB); // [8, 16 MB): [OUT][CAP] u32
    int* counts = (int*)(ws + 16 * MB);                 // 64 KB raw counts

    // zero edges (pad slots decode to val=0) + counts in one contiguous fill
    (void)hipMemsetAsync(ws + 8 * MB, 0, 8 * MB + OUT_F * sizeof(int), stream);

    int npart = (nnz + EPB - 1) / EPB;
    prep_kernel<<<npart + TBLK, 256, 0, stream>>>(x, xTh, rows, cols, wvals, nnz,
                                                  npart, edges, counts);
    accum_kernel<<<(OUT_F / 16) * 2, 256, 0, stream>>>((const unsigned int*)xTh, edges,
                                                       counts, bias, out);
}